// Round 2
// baseline (906.479 us; speedup 1.0000x reference)
//
#include <hip/hip_runtime.h>
#include <stdint.h>

// Biaffine: out[b,x,y,o] = sum_ij in1[b,x,i] w1[i,o,j] in2[b,y,j]
//                        + p1[b,x,o] + p2[b,y,o] + bias[o]
// B=8 L=256 D=512 O=128.
// Two-stage bf16 MFMA GEMM through T[b,(x,o),j]; barrier-free K-loops:
// reused operand (64 rows x K=512 = 64KB) LDS-resident, streamed operand
// loaded direct global->VGPR as MFMA fragments (16B K-contiguous per lane).

typedef unsigned short u16;
typedef __attribute__((ext_vector_type(8))) __bf16 bf16x8;
typedef __attribute__((ext_vector_type(4))) float f32x4;

__device__ __forceinline__ u16 f2bf(float f) {
    uint32_t u = __builtin_bit_cast(uint32_t, f);
    u += 0x7fffu + ((u >> 16) & 1u);       // RNE
    return (u16)(u >> 16);
}

// ---------------------------------------------------------------- cvt f32->bf16
__global__ __launch_bounds__(256) void cvt_kernel(const float* __restrict__ src,
                                                  u16* __restrict__ dst) {
    int i = blockIdx.x * 256 + threadIdx.x;      // one float4 each
    float4 v = reinterpret_cast<const float4*>(src)[i];
    uint2 r;
    r.x = (uint32_t)f2bf(v.x) | ((uint32_t)f2bf(v.y) << 16);
    r.y = (uint32_t)f2bf(v.z) | ((uint32_t)f2bf(v.w) << 16);
    reinterpret_cast<uint2*>(dst)[i] = r;
}

// ------------------------------------------------- w1 [i][n] f32 -> Wt [n][i] bf16
__global__ __launch_bounds__(256) void transw_kernel(const float* __restrict__ w1,
                                                     u16* __restrict__ Wt) {
    __shared__ float tile[64][65];
    const int n0 = blockIdx.x * 64;
    const int i0 = blockIdx.y * 64;
    const int t  = threadIdx.x;
    #pragma unroll
    for (int r = 0; r < 16; ++r) {
        int idx = r * 256 + t;
        int li = idx >> 6, ln = idx & 63;
        tile[li][ln] = w1[(size_t)(i0 + li) * 65536 + n0 + ln];
    }
    __syncthreads();
    #pragma unroll
    for (int r = 0; r < 16; ++r) {
        int idx = r * 256 + t;
        int ln = idx >> 6, li = idx & 63;
        Wt[(size_t)(n0 + ln) * 512 + i0 + li] = f2bf(tile[li][ln]);
    }
}

// ------------------------------------------- p1/p2: rank-1 terms  p[b,l,o] (f32)
__global__ __launch_bounds__(128) void pk_kernel(const float* __restrict__ in1,
                                                 const float* __restrict__ in2,
                                                 const float* __restrict__ w2,
                                                 float* __restrict__ p1,
                                                 float* __restrict__ p2) {
    const int grp = blockIdx.x;
    const float* src; const float* w; float* dst;
    if (blockIdx.y == 0) { src = in1; w = w2;               dst = p1; }
    else                 { src = in2; w = w2 + 512 * 128;   dst = p2; }
    src += (size_t)grp * 8 * 512;
    dst += (size_t)grp * 8 * 128;
    __shared__ float rows[8][512];
    const int t = threadIdx.x;
    #pragma unroll
    for (int r = 0; r < 32; ++r) {
        int idx = r * 128 + t;
        rows[idx >> 9][idx & 511] = src[idx];
    }
    __syncthreads();
    float acc[8] = {0, 0, 0, 0, 0, 0, 0, 0};
    for (int k = 0; k < 512; ++k) {
        float wv = w[k * 128 + t];
        #pragma unroll
        for (int r = 0; r < 8; ++r) acc[r] += rows[r][k] * wv;
    }
    #pragma unroll
    for (int r = 0; r < 8; ++r) dst[r * 128 + t] = acc[r];
}

// ------------------------------------------------------------- GEMM building blocks
// Stage 64 rows x 512 K bf16 (64 KB) into LDS once. Chunk-index XOR swizzle
// (low 3 bits by row) keeps global_load_lds lane-linear yet makes fragment
// ds_read_b128 at most 2-way bank-aliased (free).
__device__ __forceinline__ void stage_rows64(const u16* __restrict__ src, u16* lds) {
    const int t = threadIdx.x;
    #pragma unroll
    for (int it = 0; it < 16; ++it) {
        int c   = it * 256 + t;               // LDS 16B-chunk index (lane-linear)
        int row = c >> 6, p = c & 63;
        int g   = (p & ~7) | ((p & 7) ^ (row & 7));
        __builtin_amdgcn_global_load_lds(
            (const __attribute__((address_space(1))) void*)(src + (size_t)row * 512 + g * 8),
            (__attribute__((address_space(3))) void*)(lds + (size_t)c * 8),
            16, 0, 0);
    }
    __builtin_amdgcn_s_waitcnt(0);
    __syncthreads();
}

// Barrier-free K-loop: acc(64m x 64n per wave) += ldsA(64x512) * Bn(64 rows)^T.
// Bn = this wave's n-base row pointer (row-major, 512 bf16 K-contiguous rows).
__device__ __forceinline__ void kloop(const u16* __restrict__ Bn,
                                      const u16* lds, f32x4 acc[4][4]) {
    const int lane = threadIdx.x & 63;
    const int col = lane & 15, kg = lane >> 4;
    #pragma unroll 4
    for (int ks = 0; ks < 16; ++ks) {
        const int kc = ks * 4 + kg;
        bf16x8 af[4], bfr[4];
        #pragma unroll
        for (int mt = 0; mt < 4; ++mt) {
            int row = mt * 16 + col;
            int pos = (kc & ~7) | ((kc & 7) ^ (row & 7));
            af[mt] = *reinterpret_cast<const bf16x8*>(lds + row * 512 + pos * 8);
        }
        #pragma unroll
        for (int nt = 0; nt < 4; ++nt)
            bfr[nt] = *reinterpret_cast<const bf16x8*>(
                Bn + (size_t)(nt * 16 + col) * 512 + kc * 8);
        #pragma unroll
        for (int mt = 0; mt < 4; ++mt)
            #pragma unroll
            for (int nt = 0; nt < 4; ++nt)
                acc[mt][nt] = __builtin_amdgcn_mfma_f32_16x16x32_bf16(
                    af[mt], bfr[nt], acc[mt][nt], 0, 0, 0);
    }
}

// ---------------- stage 1: T[m=(x-row)][n=(o*512+j)] = in1 * Wt^T, bf16 out
// LDS holds the reused in1 m-tile; Wt streamed direct (L2/L3 shared across
// the 32 m-blocks that co-run per n-slice; m is the fast grid dim).
__global__ __launch_bounds__(256, 2) void gemm1_kernel(const u16* __restrict__ Ab,
                                                       const u16* __restrict__ Wt,
                                                       u16* __restrict__ T) {
    __shared__ u16 lds[32768];                    // 64 KB
    const int m0 = blockIdx.x * 64;               // rows within chunk
    const int n0 = blockIdx.y * 256;
    const int w  = threadIdx.x >> 6;
    stage_rows64(Ab + (size_t)m0 * 512, lds);
    f32x4 acc[4][4];
    #pragma unroll
    for (int i = 0; i < 4; ++i)
        #pragma unroll
        for (int j = 0; j < 4; ++j) acc[i][j] = f32x4{0.f, 0.f, 0.f, 0.f};
    kloop(Wt + ((size_t)n0 + w * 64) * 512, lds, acc);

    // epilogue: bf16 via LDS (padded stride 264) -> coalesced 16B stores
    __syncthreads();                              // done reading ldsA
    const int lane = threadIdx.x & 63;
    const int col = lane & 15, kg = lane >> 4;
    #pragma unroll
    for (int mt = 0; mt < 4; ++mt)
        #pragma unroll
        for (int nt = 0; nt < 4; ++nt) {
            int n = w * 64 + nt * 16 + col;
            #pragma unroll
            for (int r = 0; r < 4; ++r) {
                int m = mt * 16 + kg * 4 + r;
                lds[m * 264 + n] = f2bf(acc[mt][nt][r]);
            }
        }
    __syncthreads();
    const int t = threadIdx.x;
    #pragma unroll
    for (int it = 0; it < 8; ++it) {
        int c = it * 256 + t;                     // 2048 x 16B chunks
        int row = c >> 5, k = c & 31;
        *reinterpret_cast<uint4*>(T + (size_t)(m0 + row) * 65536 + n0 + k * 8) =
            *reinterpret_cast<const uint4*>(
                reinterpret_cast<const char*>(lds) + row * 528 + k * 16);
    }
}

// -------- stage 2: out[b,x,y,o] = T[(x,o),:]·in2[b,y,:] + p1 + p2 + bias
// LDS holds the streamed-once T m-tile; in2 (L2-hot, 256 KB/batch) direct.
// n-tile = all 256 y -> T read exactly once.
__global__ __launch_bounds__(256, 2) void gemm2_kernel(const u16* __restrict__ Tc,
                                                       const u16* __restrict__ B2c,
                                                       const float* __restrict__ p1c,
                                                       const float* __restrict__ p2c,
                                                       const float* __restrict__ bias,
                                                       float* __restrict__ outc) {
    __shared__ u16 lds[32768];
    const int m0 = blockIdx.x * 64;               // row within batch (x*128+o)
    const int bb = blockIdx.y;                    // chunk-local batch
    const int w  = threadIdx.x >> 6;
    stage_rows64(Tc + (size_t)bb * 16777216 + (size_t)m0 * 512, lds);
    f32x4 acc[4][4];
    #pragma unroll
    for (int i = 0; i < 4; ++i)
        #pragma unroll
        for (int j = 0; j < 4; ++j) acc[i][j] = f32x4{0.f, 0.f, 0.f, 0.f};
    kloop(B2c + (size_t)bb * 131072 + (size_t)(w * 64) * 512, lds, acc);

    const int x   = m0 >> 7;
    const int ob0 = m0 & 127;
    const float* p1b = p1c + (size_t)bb * 32768 + x * 128;
    const float* p2b = p2c + (size_t)bb * 32768;
    float* outb = outc + (size_t)bb * 8388608 + (size_t)x * 32768;

    const int lane = threadIdx.x & 63;
    const int col = lane & 15, kg = lane >> 4;
    #pragma unroll
    for (int mt = 0; mt < 4; ++mt) {
        const int o = ob0 + mt * 16 + kg * 4;
        const f32x4 pv1 = *reinterpret_cast<const f32x4*>(p1b + o);
        const f32x4 bv  = *reinterpret_cast<const f32x4*>(bias + o);
        #pragma unroll
        for (int nt = 0; nt < 4; ++nt) {
            const int y = w * 64 + nt * 16 + col;
            const f32x4 pv2 = *reinterpret_cast<const f32x4*>(p2b + (size_t)y * 128 + o);
            *reinterpret_cast<f32x4*>(outb + (size_t)y * 128 + o) =
                acc[mt][nt] + pv1 + pv2 + bv;
        }
    }
}

// ----------------------------------------------------------------------- launch
extern "C" void kernel_launch(void* const* d_in, const int* in_sizes, int n_in,
                              void* d_out, int out_size, void* d_ws, size_t ws_size,
                              hipStream_t stream) {
    const float* in1 = (const float*)d_in[0];   // 8*256*512
    const float* in2 = (const float*)d_in[1];
    const float* w1  = (const float*)d_in[2];   // 512*128*512
    const float* w2  = (const float*)d_in[3];   // 1025*128
    float* out = (float*)d_out;
    char*  ws  = (char*)d_ws;

    u16*   Wt  = (u16*)(ws);                    // 67,108,864  bf16 [n][i]
    u16*   Ab  = (u16*)(ws + 67108864);         //  2,097,152  bf16 in1
    u16*   B2b = (u16*)(ws + 69206016);         //  2,097,152  bf16 in2
    float* p1  = (float*)(ws + 71303168);       //  1,048,576
    float* p2  = (float*)(ws + 72351744);       //  1,048,576
    u16*   T   = (u16*)(ws + 73400320);         //  C * 33,554,432

    const size_t base = 73400320ull;
    int C = 1;
    if      (ws_size >= base + 8ull * 33554432ull) C = 8;
    else if (ws_size >= base + 4ull * 33554432ull) C = 4;
    else if (ws_size >= base + 2ull * 33554432ull) C = 2;

    cvt_kernel<<<1024, 256, 0, stream>>>(in1, Ab);
    cvt_kernel<<<1024, 256, 0, stream>>>(in2, B2b);
    transw_kernel<<<dim3(1024, 8), 256, 0, stream>>>(w1, Wt);
    pk_kernel<<<dim3(256, 2), 128, 0, stream>>>(in1, in2, w2, p1, p2);

    for (int b0 = 0; b0 < 8; b0 += C) {
        int Cb = (8 - b0 < C) ? (8 - b0) : C;
        // stage 1: M = Cb*256 rows (m fast dim), N = 65536, K = 512
        gemm1_kernel<<<dim3(Cb * 4, 256), 256, 0, stream>>>(
            Ab + (size_t)b0 * 131072, Wt, T);
        // stage 2: per batch M = 32768 (x,o), N = 256 (all y), K = 512
        gemm2_kernel<<<dim3(512, Cb), 256, 0, stream>>>(
            T, B2b + (size_t)b0 * 131072,
            p1 + (size_t)b0 * 32768, p2 + (size_t)b0 * 32768,
            w2 + 131072, out + (size_t)b0 * 8388608);
    }
}